// Round 13
// baseline (119.585 us; speedup 1.0000x reference)
//
#include <hip/hip_runtime.h>

typedef __attribute__((ext_vector_type(2))) __fp16 h2;
typedef __attribute__((ext_vector_type(4))) __fp16 h4;
typedef __attribute__((ext_vector_type(8))) __fp16 h8;
typedef __attribute__((ext_vector_type(4))) float f32x4;

#define LOG2E 1.44269504088896340736f

// ws layout (bytes) — identical to rounds 6/7/11/12 (verified passing)
#define WS_K    0ull            // 14*64 tiles * 8192 B
#define WS_MK   7340032ull      // 14*16 tiles * 8192 B
#define WS_VT   9175040ull      // 14*64 tiles * 512 B
#define WS_MVT  9633792ull      // 14*16 tiles * 512 B
#define WS_NEED 9748480ull

__device__ __forceinline__ h2 pkrtz(float a, float b) {
    return __builtin_bit_cast(h2, __builtin_amdgcn_cvt_pkrtz(a, b));
}

__device__ __forceinline__ void gll16(const void* g, void* l) {
    __builtin_amdgcn_global_load_lds(
        (const __attribute__((address_space(1))) unsigned int*)g,
        (__attribute__((address_space(3))) unsigned int*)l, 16, 0, 0);
}

// ---------------- Precompute (verbatim rounds 6-12, verified) ----------------
__global__ __launch_bounds__(256) void kast_pre_kernel(
    const float* __restrict__ K, const float* __restrict__ V,
    const float* __restrict__ MK, const float* __restrict__ MV,
    char* __restrict__ ws)
{
    const int id = blockIdx.x * 256 + threadIdx.x;
    if (id < 573440) {
        const bool ismk = id >= 458752;
        const int lid = ismk ? id - 458752 : id;
        const int c = lid & 7;
        const int r = (lid >> 3) & 63;
        int kt, s;
        if (ismk) { kt = (lid >> 9) & 15; s = lid >> 13; }
        else      { kt = (lid >> 9) & 63; s = lid >> 15; }
        const int b = s / 7, t = s - b * 7;
        const float* src = ismk
            ? MK + (((size_t)(b * 7 + t) * 1024 + kt * 64 + r) * 64 + c * 8)
            : K  + (((size_t)(b * 8 + t) * 4096 + kt * 64 + r) * 64 + c * 8);
        const f32x4 xa = *(const f32x4*)src;
        const f32x4 xb = *(const f32x4*)(src + 4);
        const h2 q0 = pkrtz(xa[0], xa[1]), q1 = pkrtz(xa[2], xa[3]);
        const h2 q2 = pkrtz(xb[0], xb[1]), q3 = pkrtz(xb[2], xb[3]);
        const h8 out = {q0[0], q0[1], q1[0], q1[1], q2[0], q2[1], q3[0], q3[1]};
        __fp16* dst = (__fp16*)(ws + (ismk ? WS_MK : WS_K))
                    + (size_t)(ismk ? (s * 16 + kt) : (s * 64 + kt)) * 4096
                    + r * 64 + ((c ^ (r & 7)) * 8);
        *(h8*)dst = out;
    } else {
        const int vid = id - 573440;
        const bool ismv = vid >= 57344;
        const int lid = ismv ? vid - 57344 : vid;
        const int c = lid & 15;
        const int d = (lid >> 4) & 3;
        int kt, s;
        if (ismv) { kt = (lid >> 6) & 15; s = lid >> 10; }
        else      { kt = (lid >> 6) & 63; s = lid >> 12; }
        const int b = s / 7, t = s - b * 7;
        const float* src = ismv
            ? MV + (((size_t)(b * 7 + t) * 1024 + kt * 64 + c * 4) * 3)
            : V  + (((size_t)(b * 8 + t) * 4096 + kt * 64 + c * 4) * 3);
        float f0, f1, f2, f3;
        if (d == 3) { f0 = f1 = f2 = f3 = 1.0f; }
        else { f0 = src[d]; f1 = src[3 + d]; f2 = src[6 + d]; f3 = src[9 + d]; }
        const h2 pa = pkrtz(f0, f1), pb = pkrtz(f2, f3);
        const h4 out4 = {pa[0], pa[1], pb[0], pb[1]};
        __fp16* dst = (__fp16*)(ws + (ismv ? WS_MVT : WS_VT))
                    + (size_t)(ismv ? (s * 16 + kt) : (s * 64 + kt)) * 256
                    + d * 64 + (4 * ((c >> 2) ^ d) + (c & 3)) * 4;
        *(h4*)dst = out4;
    }
}

// ---- Main: barrier-free wave-autonomous flash. 4 waves = 4 key-quarters,
// ---- each wave: all 64 block-queries, private double-buffered LDS,
// ---- wave-local counted vmcnt. Barriers ONLY at the per-phase merge.
__global__ __launch_bounds__(256) void kast_attn_kernel(
    const float* __restrict__ K,   // (2,8,4096,64) for Q
    const char* __restrict__ ws,
    float* __restrict__ OUT)       // (2,7,4096,3)
{
    __shared__ alignas(16) __fp16 sKp[4][2][32][64];   // [wave][buf] private 4KB tiles
    __shared__ float mrg[4][64][5];                    // [wave][q][{m,O0,O1,O2,l}]

    const int id = blockIdx.x;
    const int sw = (id & 7) * 112 + (id >> 3);   // XCD-chunked, bijective (896%8==0)
    const int bt = sw >> 6;
    const int qblk = sw & 63;
    const int b = bt / 7, t = bt - b * 7;

    const int tid = threadIdx.x;
    const int lane = tid & 63;
    const int w = tid >> 6;      // wave 0..3 = key-quarter
    const int col = lane & 15;
    const int g = lane >> 4;     // k-chunk group
    const int cs = col & 7;      // K-read swizzle key ((row&7)==(col&7))
    const int d3 = col & 3;      // V^T row

    // ---- Q fragments: 4 M-tiles (all 64 queries), scaled by log2(e) ----
    h8 aq[4][2];
#pragma unroll
    for (int mt = 0; mt < 4; ++mt) {
        const float* qp = K + (((size_t)b * 8 + (t + 1)) * 4096
                         + (size_t)(qblk * 64 + mt * 16 + col)) * 64;
#pragma unroll
        for (int ch = 0; ch < 2; ++ch) {
            const int cc = ch * 32 + g * 8;
            const f32x4 xa = *(const f32x4*)&qp[cc];
            const f32x4 xb = *(const f32x4*)&qp[cc + 4];
            const h2 p0 = pkrtz(xa[0] * LOG2E, xa[1] * LOG2E);
            const h2 p1 = pkrtz(xa[2] * LOG2E, xa[3] * LOG2E);
            const h2 p2 = pkrtz(xb[0] * LOG2E, xb[1] * LOG2E);
            const h2 p3 = pkrtz(xb[2] * LOG2E, xb[3] * LOG2E);
            aq[mt][ch] = (h8){p0[0], p0[1], p1[0], p1[1], p2[0], p2[1], p3[0], p3[1]};
        }
    }

    float oa0 = 0.f, oa1 = 0.f, oa2 = 0.f;   // merge accumulators (tid<64)

#pragma unroll
    for (int phase = 0; phase < 2; ++phase) {
        const int n = phase ? 8 : 32;        // 32-key tiles per quarter
        const float wgt = phase ? 0.2f : 0.8f;
        const int keys_off = w * (phase ? 256 : 1024);
        const char* kseg = ws + (phase ? (WS_MK + (size_t)bt * 16 * 8192)
                                       : (WS_K  + (size_t)bt * 64 * 8192))
                         + (size_t)keys_off * 128;
        const char* vseg = ws + (phase ? (WS_MVT + (size_t)bt * 16 * 512)
                                       : (WS_VT  + (size_t)bt * 64 * 512))
                         + (size_t)(keys_off >> 6) * 512;

        // ---- prologue: stage tile 0 (4KB, 4x gll16) + V(0) reg loads ----
        {
            const char* ksrc = kseg + lane * 16;
            char* kdst = ((char*)&sKp[w][0][0][0]) + lane * 16;
#pragma unroll
            for (int i = 0; i < 4; ++i) gll16(ksrc + i * 1024, kdst + i * 1024);
        }
        const char* vt0 = vseg + d3 * 128;
        h4 v0 = *(const h4*)(vt0 + (4 * (0 ^ d3) + g) * 8);
        h4 v1 = *(const h4*)(vt0 + (4 * (1 ^ d3) + g) * 8);

        float mrun[4] = {-1e30f, -1e30f, -1e30f, -1e30f};
        f32x4 O[4];
#pragma unroll
        for (int mt = 0; mt < 4; ++mt) O[mt] = (f32x4){0.f, 0.f, 0.f, 0.f};

        for (int kt = 0; kt < n; ++kt) {
            const int cur = kt & 1;
            h4 nv0 = v0, nv1 = v1;

            if (kt + 1 < n) {
                // issue next tile's K staging (4 gll16) + V reg loads (2)
                const char* ksrc = kseg + (size_t)(kt + 1) * 4096 + lane * 16;
                char* kdst = ((char*)&sKp[w][cur ^ 1][0][0]) + lane * 16;
#pragma unroll
                for (int i = 0; i < 4; ++i) gll16(ksrc + i * 1024, kdst + i * 1024);
                const int sub = (kt + 1) & 1;
                const char* vt = vseg + (size_t)((kt + 1) >> 1) * 512 + d3 * 128;
                nv0 = *(const h4*)(vt + (4 * ((sub * 2 + 0) ^ d3) + g) * 8);
                nv1 = *(const h4*)(vt + (4 * ((sub * 2 + 1) ^ d3) + g) * 8);
                // wave-local: 6 newer ops (4 gll16 + 2 V) stay in flight;
                // everything older (tile kt's 4 gll16 + 2 V) completes.
                asm volatile("s_waitcnt vmcnt(6)" ::: "memory");
            } else {
                asm volatile("s_waitcnt vmcnt(0)" ::: "memory");
            }
            __builtin_amdgcn_sched_barrier(0);

            // ---- QK^T: 4 ds_read_b128 feed 16 MFMA (A=K frag, B=Q frag) ----
            f32x4 acc[4][2];
#pragma unroll
            for (int mt = 0; mt < 4; ++mt)
#pragma unroll
                for (int nt = 0; nt < 2; ++nt) acc[mt][nt] = (f32x4){0.f,0.f,0.f,0.f};
            __builtin_amdgcn_s_setprio(1);
#pragma unroll
            for (int ch = 0; ch < 2; ++ch) {
                h8 bh[2];
#pragma unroll
                for (int nt = 0; nt < 2; ++nt)
                    bh[nt] = *(const h8*)&sKp[w][cur][nt * 16 + col][((ch * 4 + g) ^ cs) * 8];
#pragma unroll
                for (int mt = 0; mt < 4; ++mt)
#pragma unroll
                    for (int nt = 0; nt < 2; ++nt)
                        acc[mt][nt] = __builtin_amdgcn_mfma_f32_16x16x32_f16(bh[nt], aq[mt][ch], acc[mt][nt], 0, 0, 0);
            }
            __builtin_amdgcn_s_setprio(0);
            // lane holds S[key = nt*16 + 4g + j][q = mt*16 + col]

            // ---- per-query softmax, branchless, 4 independent chains ----
#pragma unroll
            for (int mt = 0; mt < 4; ++mt) {
                float tm = fmaxf(fmaxf(fmaxf(acc[mt][0][0], acc[mt][0][1]),
                                       fmaxf(acc[mt][0][2], acc[mt][0][3])),
                                 fmaxf(fmaxf(acc[mt][1][0], acc[mt][1][1]),
                                       fmaxf(acc[mt][1][2], acc[mt][1][3])));
                tm = fmaxf(tm, __shfl_xor(tm, 16));
                tm = fmaxf(tm, __shfl_xor(tm, 32));
                const float m = fmaxf(mrun[mt], tm);
                const float sc = __builtin_amdgcn_exp2f(mrun[mt] - m);  // 1.0 if no new max
                O[mt] *= sc;
                mrun[mt] = m;
            }

            // ---- P = exp2(S-m) -> fp16, PV + lsum on MFMA pipe ----
#pragma unroll
            for (int nt = 0; nt < 2; ++nt) {
                const h4 vf = nt ? v1 : v0;
#pragma unroll
                for (int mt = 0; mt < 4; ++mt) {
                    const float p0 = __builtin_amdgcn_exp2f(acc[mt][nt][0] - mrun[mt]);
                    const float p1 = __builtin_amdgcn_exp2f(acc[mt][nt][1] - mrun[mt]);
                    const float p2 = __builtin_amdgcn_exp2f(acc[mt][nt][2] - mrun[mt]);
                    const float p3 = __builtin_amdgcn_exp2f(acc[mt][nt][3] - mrun[mt]);
                    const h2 pa = pkrtz(p0, p1), pb = pkrtz(p2, p3);
                    const h4 pf = (h4){pa[0], pa[1], pb[0], pb[1]};
                    O[mt] = __builtin_amdgcn_mfma_f32_16x16x16f16(vf, pf, O[mt], 0, 0, 0);
                }
            }

            v0 = nv0; v1 = nv1;
            // NO barrier: LDS buffers are wave-private; vmcnt is wave-local.
        }

        // ---- partials to LDS; exact 4-way flash merge (2 barriers/phase) ----
        if (g == 0) {
#pragma unroll
            for (int mt = 0; mt < 4; ++mt) {
                float* m5 = &mrg[w][mt * 16 + col][0];
                m5[0] = mrun[mt];
                m5[1] = O[mt][0]; m5[2] = O[mt][1]; m5[3] = O[mt][2]; m5[4] = O[mt][3];
            }
        }
        __syncthreads();
        if (tid < 64) {
            float m = -1e30f;
#pragma unroll
            for (int q4 = 0; q4 < 4; ++q4) m = fmaxf(m, mrg[q4][tid][0]);
            float l = 0.f, r0 = 0.f, r1 = 0.f, r2 = 0.f;
#pragma unroll
            for (int q4 = 0; q4 < 4; ++q4) {
                const float* m5 = &mrg[q4][tid][0];
                const float e = __builtin_amdgcn_exp2f(m5[0] - m);
                r0 += m5[1] * e; r1 += m5[2] * e; r2 += m5[3] * e;
                l  += m5[4] * e;
            }
            const float inv = wgt / l;
            oa0 += r0 * inv; oa1 += r1 * inv; oa2 += r2 * inv;
        }
        __syncthreads();   // mrg free before next phase's partial writes
    }

    if (tid < 64) {
        const int q = qblk * 64 + tid;
        float* op = OUT + (((size_t)b * 7 + t) * 4096 + (size_t)q) * 3;
        op[0] = oa0; op[1] = oa1; op[2] = oa2;
    }
}

// ---------------- Fallback (round-4 kernel, known-good) if ws too small ----------------
__global__ __launch_bounds__(256) void kast_attn_fb(
    const float* __restrict__ K, const float* __restrict__ V,
    const float* __restrict__ MK, const float* __restrict__ MV,
    float* __restrict__ OUT)
{
    __shared__ alignas(16) __fp16 sK[2][64][64];
    __shared__ alignas(16) __fp16 sVT[2][4][68];

    const int id = blockIdx.x;
    const int sw = (id & 7) * 112 + (id >> 3);
    const int bt = sw >> 6;
    const int qblk = sw & 63;
    const int b = bt / 7, t = bt % 7;

    const int tid = threadIdx.x;
    const int lane = tid & 63;
    const int w = tid >> 6;
    const int col = lane & 15;
    const int g = lane >> 4;

    const int r = tid >> 2;
    const int c0 = (tid & 3) * 16;
    const int rs = (r & 7) << 3;
    const unsigned vr = (unsigned)tid / 3u;
    const unsigned vd = (unsigned)tid - vr * 3u;

    if (tid < 128) sVT[tid >> 6][3][tid & 63] = (__fp16)1.0f;

    const float* Qbase = K + (((size_t)b * 8 + (t + 1)) * 4096) * 64;
    h8 aq[2];
    {
        const int qrow = qblk * 64 + w * 16 + col;
        const float* qp = Qbase + (size_t)qrow * 64;
#pragma unroll
        for (int ch = 0; ch < 2; ++ch) {
            const int cc = ch * 32 + g * 8;
            const f32x4 xa = *(const f32x4*)&qp[cc];
            const f32x4 xb = *(const f32x4*)&qp[cc + 4];
            const h2 p0 = pkrtz(xa[0] * LOG2E, xa[1] * LOG2E);
            const h2 p1 = pkrtz(xa[2] * LOG2E, xa[3] * LOG2E);
            const h2 p2 = pkrtz(xb[0] * LOG2E, xb[1] * LOG2E);
            const h2 p3 = pkrtz(xb[2] * LOG2E, xb[3] * LOG2E);
            aq[ch] = (h8){p0[0], p0[1], p1[0], p1[1], p2[0], p2[1], p3[0], p3[1]};
        }
    }

    float outc0 = 0.f, outc1 = 0.f, outc2 = 0.f;

    for (int phase = 0; phase < 2; ++phase) {
        const float* kp; const float* vp; int ntile; float wgt;
        if (phase == 0) {
            kp = K + (((size_t)b * 8 + t) * 4096) * 64;
            vp = V + (((size_t)b * 8 + t) * 4096) * 3;
            ntile = 64; wgt = 0.8f;
        } else {
            kp = MK + (((size_t)b * 7 + t) * 1024) * 64;
            vp = MV + (((size_t)b * 7 + t) * 1024) * 3;
            ntile = 16; wgt = 0.2f;
        }
        {
            const float* src = kp + ((size_t)r) * 64 + c0;
            const f32x4* s4 = (const f32x4*)src;
            const f32x4 ra = s4[0], rb = s4[1], rc = s4[2], rd = s4[3];
            const h2 q0 = pkrtz(ra[0], ra[1]), q1 = pkrtz(ra[2], ra[3]);
            const h2 q2 = pkrtz(rb[0], rb[1]), q3 = pkrtz(rb[2], rb[3]);
            const h2 q4 = pkrtz(rc[0], rc[1]), q5 = pkrtz(rc[2], rc[3]);
            const h2 q6 = pkrtz(rd[0], rd[1]), q7 = pkrtz(rd[2], rd[3]);
            *(h8*)&sK[0][r][c0 ^ rs] = (h8){q0[0], q0[1], q1[0], q1[1], q2[0], q2[1], q3[0], q3[1]};
            *(h8*)&sK[0][r][(c0 + 8) ^ rs] = (h8){q4[0], q4[1], q5[0], q5[1], q6[0], q6[1], q7[0], q7[1]};
            if (tid < 192) sVT[0][vd][vr] = (__fp16)vp[tid];
        }
        __syncthreads();

        float mrun = -1e30f;
        f32x4 O = (f32x4){0.f, 0.f, 0.f, 0.f};

        for (int kt = 0; kt < ntile; ++kt) {
            const int cur = kt & 1;
            const bool have = (kt + 1) < ntile;
            f32x4 ra, rb, rc, rd; float rv = 0.f;
            if (have) {
                const float* src = kp + ((size_t)(kt + 1) * 64 + r) * 64 + c0;
                const f32x4* s4 = (const f32x4*)src;
                ra = s4[0]; rb = s4[1]; rc = s4[2]; rd = s4[3];
                if (tid < 192) rv = vp[(size_t)(kt + 1) * 192 + tid];
            }
            f32x4 acc[4];
#pragma unroll
            for (int nt = 0; nt < 4; ++nt) acc[nt] = (f32x4){0.f, 0.f, 0.f, 0.f};
#pragma unroll
            for (int ch = 0; ch < 2; ++ch) {
                h8 bh[4];
#pragma unroll
                for (int nt = 0; nt < 4; ++nt) {
                    const int rr = nt * 16 + col;
                    const int cc = (ch * 32 + g * 8) ^ ((rr & 7) << 3);
                    bh[nt] = *(const h8*)&sK[cur][rr][cc];
                }
#pragma unroll
                for (int nt = 0; nt < 4; ++nt)
                    acc[nt] = __builtin_amdgcn_mfma_f32_16x16x32_f16(bh[nt], aq[ch], acc[nt], 0, 0, 0);
            }
            {
                float tm = acc[0][0];
#pragma unroll
                for (int nt = 0; nt < 4; ++nt)
#pragma unroll
                    for (int j = 0; j < 4; ++j) tm = fmaxf(tm, acc[nt][j]);
                tm = fmaxf(tm, __shfl_xor(tm, 16));
                tm = fmaxf(tm, __shfl_xor(tm, 32));
                if (!__all(tm <= mrun)) {
                    const float mnew = fmaxf(mrun, tm);
                    const float sc = __builtin_amdgcn_exp2f(mrun - mnew);
                    O *= sc;
                    mrun = mnew;
                }
            }
#pragma unroll
            for (int nt = 0; nt < 4; ++nt) {
                const float p0 = __builtin_amdgcn_exp2f(acc[nt][0] - mrun);
                const float p1 = __builtin_amdgcn_exp2f(acc[nt][1] - mrun);
                const float p2 = __builtin_amdgcn_exp2f(acc[nt][2] - mrun);
                const float p3 = __builtin_amdgcn_exp2f(acc[nt][3] - mrun);
                const h2 pa = pkrtz(p0, p1), pb = pkrtz(p2, p3);
                const h4 pf = (h4){pa[0], pa[1], pb[0], pb[1]};
                const h4 vf = *(const h4*)&sVT[cur][col & 3][nt * 16 + 4 * g];
                O = __builtin_amdgcn_mfma_f32_16x16x16f16(vf, pf, O, 0, 0, 0);
            }
            if (have) {
                const int nb = cur ^ 1;
                const h2 q0 = pkrtz(ra[0], ra[1]), q1 = pkrtz(ra[2], ra[3]);
                const h2 q2 = pkrtz(rb[0], rb[1]), q3 = pkrtz(rb[2], rb[3]);
                const h2 q4 = pkrtz(rc[0], rc[1]), q5 = pkrtz(rc[2], rc[3]);
                const h2 q6 = pkrtz(rd[0], rd[1]), q7 = pkrtz(rd[2], rd[3]);
                *(h8*)&sK[nb][r][c0 ^ rs] = (h8){q0[0], q0[1], q1[0], q1[1], q2[0], q2[1], q3[0], q3[1]};
                *(h8*)&sK[nb][r][(c0 + 8) ^ rs] = (h8){q4[0], q4[1], q5[0], q5[1], q6[0], q6[1], q7[0], q7[1]};
                if (tid < 192) sVT[nb][vd][vr] = (__fp16)rv;
            }
            __syncthreads();
        }
        const float inv = wgt / O[3];
        outc0 += O[0] * inv;
        outc1 += O[1] * inv;
        outc2 += O[2] * inv;
    }

    if (g == 0) {
        const int q = qblk * 64 + w * 16 + col;
        float* op = OUT + (((size_t)b * 7 + t) * 4096 + (size_t)q) * 3;
        op[0] = outc0; op[1] = outc1; op[2] = outc2;
    }
}

extern "C" void kernel_launch(void* const* d_in, const int* in_sizes, int n_in,
                              void* d_out, int out_size, void* d_ws, size_t ws_size,
                              hipStream_t stream) {
    const float* K  = (const float*)d_in[0];
    const float* V  = (const float*)d_in[1];
    const float* MK = (const float*)d_in[2];
    const float* MV = (const float*)d_in[3];
    float* OUT = (float*)d_out;
    if (ws_size >= WS_NEED) {
        hipLaunchKernelGGL(kast_pre_kernel, dim3(2520), dim3(256), 0, stream,
                           K, V, MK, MV, (char*)d_ws);
        hipLaunchKernelGGL(kast_attn_kernel, dim3(896), dim3(256), 0, stream,
                           K, (const char*)d_ws, OUT);
    } else {
        hipLaunchKernelGGL(kast_attn_fb, dim3(896), dim3(256), 0, stream,
                           K, V, MK, MV, OUT);
    }
}

// Round 14
// 98.289 us; speedup vs baseline: 1.2167x; 1.2167x over previous
//
#include <hip/hip_runtime.h>

typedef __attribute__((ext_vector_type(2))) __fp16 h2;
typedef __attribute__((ext_vector_type(4))) __fp16 h4;
typedef __attribute__((ext_vector_type(8))) __fp16 h8;
typedef __attribute__((ext_vector_type(4))) float f32x4;

#define LOG2E 1.44269504088896340736f

// ws layout (bytes) — identical to rounds 6-13 (verified passing)
#define WS_K    0ull            // 14*64 tiles * 8192 B
#define WS_MK   7340032ull      // 14*16 tiles * 8192 B
#define WS_VT   9175040ull      // 14*64 tiles * 512 B
#define WS_MVT  9633792ull      // 14*16 tiles * 512 B
#define WS_NEED 9748480ull

__device__ __forceinline__ h2 pkrtz(float a, float b) {
    return __builtin_bit_cast(h2, __builtin_amdgcn_cvt_pkrtz(a, b));
}

// ---------------- Precompute (verbatim rounds 6-13, verified) ----------------
__global__ __launch_bounds__(256) void kast_pre_kernel(
    const float* __restrict__ K, const float* __restrict__ V,
    const float* __restrict__ MK, const float* __restrict__ MV,
    char* __restrict__ ws)
{
    const int id = blockIdx.x * 256 + threadIdx.x;
    if (id < 573440) {
        const bool ismk = id >= 458752;
        const int lid = ismk ? id - 458752 : id;
        const int c = lid & 7;
        const int r = (lid >> 3) & 63;
        int kt, s;
        if (ismk) { kt = (lid >> 9) & 15; s = lid >> 13; }
        else      { kt = (lid >> 9) & 63; s = lid >> 15; }
        const int b = s / 7, t = s - b * 7;
        const float* src = ismk
            ? MK + (((size_t)(b * 7 + t) * 1024 + kt * 64 + r) * 64 + c * 8)
            : K  + (((size_t)(b * 8 + t) * 4096 + kt * 64 + r) * 64 + c * 8);
        const f32x4 xa = *(const f32x4*)src;
        const f32x4 xb = *(const f32x4*)(src + 4);
        const h2 q0 = pkrtz(xa[0], xa[1]), q1 = pkrtz(xa[2], xa[3]);
        const h2 q2 = pkrtz(xb[0], xb[1]), q3 = pkrtz(xb[2], xb[3]);
        const h8 out = {q0[0], q0[1], q1[0], q1[1], q2[0], q2[1], q3[0], q3[1]};
        __fp16* dst = (__fp16*)(ws + (ismk ? WS_MK : WS_K))
                    + (size_t)(ismk ? (s * 16 + kt) : (s * 64 + kt)) * 4096
                    + r * 64 + ((c ^ (r & 7)) * 8);
        *(h8*)dst = out;
    } else {
        const int vid = id - 573440;
        const bool ismv = vid >= 57344;
        const int lid = ismv ? vid - 57344 : vid;
        const int c = lid & 15;
        const int d = (lid >> 4) & 3;
        int kt, s;
        if (ismv) { kt = (lid >> 6) & 15; s = lid >> 10; }
        else      { kt = (lid >> 6) & 63; s = lid >> 12; }
        const int b = s / 7, t = s - b * 7;
        const float* src = ismv
            ? MV + (((size_t)(b * 7 + t) * 1024 + kt * 64 + c * 4) * 3)
            : V  + (((size_t)(b * 8 + t) * 4096 + kt * 64 + c * 4) * 3);
        float f0, f1, f2, f3;
        if (d == 3) { f0 = f1 = f2 = f3 = 1.0f; }
        else { f0 = src[d]; f1 = src[3 + d]; f2 = src[6 + d]; f3 = src[9 + d]; }
        const h2 pa = pkrtz(f0, f1), pb = pkrtz(f2, f3);
        const h4 out4 = {pa[0], pa[1], pb[0], pb[1]};
        __fp16* dst = (__fp16*)(ws + (ismv ? WS_MVT : WS_VT))
                    + (size_t)(ismv ? (s * 16 + kt) : (s * 64 + kt)) * 256
                    + d * 64 + (4 * ((c >> 2) ^ d) + (c & 3)) * 4;
        *(h4*)dst = out4;
    }
}

// ---- Main: register-staged barrier-free flash. Grid 1792 = 14 bt x 128 q-blocks
// ---- of 32. Block: 4 waves = 4 key-quarters, each wave 32q x quarter-keys.
// ---- K/V fragments loaded straight from pre-swizzled ws into VGPRs (L2-hot);
// ---- no K-loop LDS, no K-loop barriers, no hand waitcnt (compiler-managed).
__global__ __launch_bounds__(256, 4) void kast_attn_kernel(
    const float* __restrict__ K,   // (2,8,4096,64) for Q
    const char* __restrict__ ws,
    float* __restrict__ OUT)       // (2,7,4096,3)
{
    __shared__ float mrg[4][32][5];   // [wave][q][{m,O0,O1,O2,l}]

    const int id = blockIdx.x;
    const int sw = (id & 7) * 224 + (id >> 3);   // XCD-chunked, bijective (1792%8==0)
    const int bt = sw >> 7;        // 0..13
    const int qblk = sw & 127;     // 0..127 (32 queries each)
    const int b = bt / 7, t = bt - b * 7;

    const int tid = threadIdx.x;
    const int lane = tid & 63;
    const int w = tid >> 6;        // wave 0..3 = key-quarter
    const int col = lane & 15;
    const int g = lane >> 4;       // k-chunk group
    const int cs = col & 7;        // swizzle key (row&7 == col&7)
    const int d3 = col & 3;        // V^T row

    // per-lane constant K-fragment byte offsets within a 4KB 32-key tile
    const int a00 = col * 128 + ((g ^ cs) * 16);            // ch0 nt0
    const int a10 = col * 128 + (((4 + g) ^ cs) * 16);      // ch1 nt0
    // nt1 adds +2048
    // per-lane constant V offsets within a 512B 64-key V-tile (after +d3*128)
    const int ov0 = (4 * (0 ^ d3) + g) * 8;   // nt2=0 (even tile, nt0)
    const int ov1 = (4 * (1 ^ d3) + g) * 8;   // nt2=1 (even tile, nt1)
    const int ov2 = (4 * (2 ^ d3) + g) * 8;   // nt2=2 (odd tile, nt0)
    const int ov3 = (4 * (3 ^ d3) + g) * 8;   // nt2=3 (odd tile, nt1)

    // ---- Q fragments (B operand), 2 M-tiles, scaled by log2(e) ----
    h8 aq00, aq01, aq10, aq11;     // aq[mt][ch]
    {
        const float* qp0 = K + (((size_t)b * 8 + (t + 1)) * 4096
                          + (size_t)(qblk * 32 + col)) * 64;
        const float* qp1 = qp0 + 16 * 64;
#pragma unroll
        for (int mt = 0; mt < 2; ++mt) {
            const float* qp = mt ? qp1 : qp0;
#pragma unroll
            for (int ch = 0; ch < 2; ++ch) {
                const int cc = ch * 32 + g * 8;
                const f32x4 xa = *(const f32x4*)&qp[cc];
                const f32x4 xb = *(const f32x4*)&qp[cc + 4];
                const h2 p0 = pkrtz(xa[0] * LOG2E, xa[1] * LOG2E);
                const h2 p1 = pkrtz(xa[2] * LOG2E, xa[3] * LOG2E);
                const h2 p2 = pkrtz(xb[0] * LOG2E, xb[1] * LOG2E);
                const h2 p3 = pkrtz(xb[2] * LOG2E, xb[3] * LOG2E);
                const h8 f = {p0[0], p0[1], p1[0], p1[1], p2[0], p2[1], p3[0], p3[1]};
                if (mt == 0 && ch == 0) aq00 = f;
                else if (mt == 0)       aq01 = f;
                else if (ch == 0)       aq10 = f;
                else                    aq11 = f;
            }
        }
    }

    float oa0 = 0.f, oa1 = 0.f, oa2 = 0.f;

#pragma unroll
    for (int phase = 0; phase < 2; ++phase) {
        const int n = phase ? 8 : 32;                 // 32-key tiles per quarter
        const float wgt = phase ? 0.2f : 0.8f;
        const char* kbase = phase
            ? ws + WS_MK  + (size_t)bt * 131072 + (size_t)w * 32768
            : ws + WS_K   + (size_t)bt * 524288 + (size_t)w * 131072;
        const char* vbase = (phase
            ? ws + WS_MVT + (size_t)bt * 8192  + (size_t)w * 2048
            : ws + WS_VT  + (size_t)bt * 32768 + (size_t)w * 8192) + d3 * 128;

        float mrun0 = -1e30f, mrun1 = -1e30f;
        f32x4 O0 = (f32x4){0.f,0.f,0.f,0.f}, O1 = (f32x4){0.f,0.f,0.f,0.f};

        // prologue: tile 0 fragments -> A regs
        h8 kA00, kA01, kA10, kA11; h4 vA0, vA1;
        {
            const char* tb = kbase;
            kA00 = *(const h8*)(tb + a00);
            kA01 = *(const h8*)(tb + a00 + 2048);
            kA10 = *(const h8*)(tb + a10);
            kA11 = *(const h8*)(tb + a10 + 2048);
            vA0 = *(const h4*)(vbase + ov0);
            vA1 = *(const h4*)(vbase + ov1);
        }

#define COMPUTE(kf00, kf01, kf10, kf11, v0, v1)                                   \
        {                                                                         \
            f32x4 c00 = (f32x4){0.f,0.f,0.f,0.f}, c01 = c00, c10 = c00, c11 = c00;\
            __builtin_amdgcn_s_setprio(1);                                        \
            c00 = __builtin_amdgcn_mfma_f32_16x16x32_f16(kf00, aq00, c00, 0,0,0); \
            c01 = __builtin_amdgcn_mfma_f32_16x16x32_f16(kf01, aq00, c01, 0,0,0); \
            c10 = __builtin_amdgcn_mfma_f32_16x16x32_f16(kf00, aq10, c10, 0,0,0); \
            c11 = __builtin_amdgcn_mfma_f32_16x16x32_f16(kf01, aq10, c11, 0,0,0); \
            c00 = __builtin_amdgcn_mfma_f32_16x16x32_f16(kf10, aq01, c00, 0,0,0); \
            c01 = __builtin_amdgcn_mfma_f32_16x16x32_f16(kf11, aq01, c01, 0,0,0); \
            c10 = __builtin_amdgcn_mfma_f32_16x16x32_f16(kf10, aq11, c10, 0,0,0); \
            c11 = __builtin_amdgcn_mfma_f32_16x16x32_f16(kf11, aq11, c11, 0,0,0); \
            __builtin_amdgcn_s_setprio(0);                                        \
            float tm0 = fmaxf(fmaxf(fmaxf(c00[0], c00[1]), fmaxf(c00[2], c00[3])),\
                              fmaxf(fmaxf(c01[0], c01[1]), fmaxf(c01[2], c01[3])));\
            float tm1 = fmaxf(fmaxf(fmaxf(c10[0], c10[1]), fmaxf(c10[2], c10[3])),\
                              fmaxf(fmaxf(c11[0], c11[1]), fmaxf(c11[2], c11[3])));\
            float s0 = __shfl_xor(tm0, 16), s1 = __shfl_xor(tm1, 16);             \
            tm0 = fmaxf(tm0, s0); tm1 = fmaxf(tm1, s1);                           \
            s0 = __shfl_xor(tm0, 32); s1 = __shfl_xor(tm1, 32);                   \
            tm0 = fmaxf(tm0, s0); tm1 = fmaxf(tm1, s1);                           \
            const float m0 = fmaxf(mrun0, tm0), m1 = fmaxf(mrun1, tm1);           \
            const float r0 = __builtin_amdgcn_exp2f(mrun0 - m0);                  \
            const float r1 = __builtin_amdgcn_exp2f(mrun1 - m1);                  \
            O0 *= r0; O1 *= r1; mrun0 = m0; mrun1 = m1;                           \
            {                                                                     \
                const float e0 = __builtin_amdgcn_exp2f(c00[0] - mrun0);          \
                const float e1 = __builtin_amdgcn_exp2f(c00[1] - mrun0);          \
                const float e2 = __builtin_amdgcn_exp2f(c00[2] - mrun0);          \
                const float e3 = __builtin_amdgcn_exp2f(c00[3] - mrun0);          \
                const h2 pa = pkrtz(e0, e1), pb = pkrtz(e2, e3);                  \
                const h4 pf = (h4){pa[0], pa[1], pb[0], pb[1]};                   \
                O0 = __builtin_amdgcn_mfma_f32_16x16x16f16(v0, pf, O0, 0, 0, 0);  \
            }                                                                     \
            {                                                                     \
                const float e0 = __builtin_amdgcn_exp2f(c01[0] - mrun0);          \
                const float e1 = __builtin_amdgcn_exp2f(c01[1] - mrun0);          \
                const float e2 = __builtin_amdgcn_exp2f(c01[2] - mrun0);          \
                const float e3 = __builtin_amdgcn_exp2f(c01[3] - mrun0);          \
                const h2 pa = pkrtz(e0, e1), pb = pkrtz(e2, e3);                  \
                const h4 pf = (h4){pa[0], pa[1], pb[0], pb[1]};                   \
                O0 = __builtin_amdgcn_mfma_f32_16x16x16f16(v1, pf, O0, 0, 0, 0);  \
            }                                                                     \
            {                                                                     \
                const float e0 = __builtin_amdgcn_exp2f(c10[0] - mrun1);          \
                const float e1 = __builtin_amdgcn_exp2f(c10[1] - mrun1);          \
                const float e2 = __builtin_amdgcn_exp2f(c10[2] - mrun1);          \
                const float e3 = __builtin_amdgcn_exp2f(c10[3] - mrun1);          \
                const h2 pa = pkrtz(e0, e1), pb = pkrtz(e2, e3);                  \
                const h4 pf = (h4){pa[0], pa[1], pb[0], pb[1]};                   \
                O1 = __builtin_amdgcn_mfma_f32_16x16x16f16(v0, pf, O1, 0, 0, 0);  \
            }                                                                     \
            {                                                                     \
                const float e0 = __builtin_amdgcn_exp2f(c11[0] - mrun1);          \
                const float e1 = __builtin_amdgcn_exp2f(c11[1] - mrun1);          \
                const float e2 = __builtin_amdgcn_exp2f(c11[2] - mrun1);          \
                const float e3 = __builtin_amdgcn_exp2f(c11[3] - mrun1);          \
                const h2 pa = pkrtz(e0, e1), pb = pkrtz(e2, e3);                  \
                const h4 pf = (h4){pa[0], pa[1], pb[0], pb[1]};                   \
                O1 = __builtin_amdgcn_mfma_f32_16x16x16f16(v1, pf, O1, 0, 0, 0);  \
            }                                                                     \
        }

        for (int kt = 0; kt < n; kt += 2) {
            // issue B loads (tile kt+1; same 512B V-tile, odd half: ov2/ov3)
            h8 kB00, kB01, kB10, kB11; h4 vB0, vB1;
            {
                const char* tb = kbase + (size_t)(kt + 1) * 4096;
                kB00 = *(const h8*)(tb + a00);
                kB01 = *(const h8*)(tb + a00 + 2048);
                kB10 = *(const h8*)(tb + a10);
                kB11 = *(const h8*)(tb + a10 + 2048);
                const char* vt = vbase + (size_t)(kt >> 1) * 512;
                vB0 = *(const h4*)(vt + ov2);
                vB1 = *(const h4*)(vt + ov3);
            }
            // compute A (tile kt)
            COMPUTE(kA00, kA01, kA10, kA11, vA0, vA1);
            // issue next A loads (tile kt+2)
            if (kt + 2 < n) {
                const char* tb = kbase + (size_t)(kt + 2) * 4096;
                kA00 = *(const h8*)(tb + a00);
                kA01 = *(const h8*)(tb + a00 + 2048);
                kA10 = *(const h8*)(tb + a10);
                kA11 = *(const h8*)(tb + a10 + 2048);
                const char* vt = vbase + (size_t)((kt + 2) >> 1) * 512;
                vA0 = *(const h4*)(vt + ov0);
                vA1 = *(const h4*)(vt + ov1);
            }
            // compute B (tile kt+1)
            COMPUTE(kB00, kB01, kB10, kB11, vB0, vB1);
        }
#undef COMPUTE

        // ---- partials to LDS; exact 4-way flash merge (2 barriers/phase) ----
        if (g == 0) {
            float* m5a = &mrg[w][col][0];
            m5a[0] = mrun0;
            m5a[1] = O0[0]; m5a[2] = O0[1]; m5a[3] = O0[2]; m5a[4] = O0[3];
            float* m5b = &mrg[w][16 + col][0];
            m5b[0] = mrun1;
            m5b[1] = O1[0]; m5b[2] = O1[1]; m5b[3] = O1[2]; m5b[4] = O1[3];
        }
        __syncthreads();
        if (tid < 32) {
            float m = -1e30f;
#pragma unroll
            for (int q4 = 0; q4 < 4; ++q4) m = fmaxf(m, mrg[q4][tid][0]);
            float l = 0.f, r0 = 0.f, r1 = 0.f, r2 = 0.f;
#pragma unroll
            for (int q4 = 0; q4 < 4; ++q4) {
                const float* m5 = &mrg[q4][tid][0];
                const float e = __builtin_amdgcn_exp2f(m5[0] - m);
                r0 += m5[1] * e; r1 += m5[2] * e; r2 += m5[3] * e;
                l  += m5[4] * e;
            }
            const float inv = wgt / l;
            oa0 += r0 * inv; oa1 += r1 * inv; oa2 += r2 * inv;
        }
        __syncthreads();   // mrg free before next phase's partial writes
    }

    if (tid < 32) {
        const int q = qblk * 32 + tid;
        float* op = OUT + (((size_t)b * 7 + t) * 4096 + (size_t)q) * 3;
        op[0] = oa0; op[1] = oa1; op[2] = oa2;
    }
}

// ---------------- Fallback (round-4 kernel, known-good) if ws too small ----------------
__global__ __launch_bounds__(256) void kast_attn_fb(
    const float* __restrict__ K, const float* __restrict__ V,
    const float* __restrict__ MK, const float* __restrict__ MV,
    float* __restrict__ OUT)
{
    __shared__ alignas(16) __fp16 sK[2][64][64];
    __shared__ alignas(16) __fp16 sVT[2][4][68];

    const int id = blockIdx.x;
    const int sw = (id & 7) * 112 + (id >> 3);
    const int bt = sw >> 6;
    const int qblk = sw & 63;
    const int b = bt / 7, t = bt % 7;

    const int tid = threadIdx.x;
    const int lane = tid & 63;
    const int w = tid >> 6;
    const int col = lane & 15;
    const int g = lane >> 4;

    const int r = tid >> 2;
    const int c0 = (tid & 3) * 16;
    const int rs = (r & 7) << 3;
    const unsigned vr = (unsigned)tid / 3u;
    const unsigned vd = (unsigned)tid - vr * 3u;

    if (tid < 128) sVT[tid >> 6][3][tid & 63] = (__fp16)1.0f;

    const float* Qbase = K + (((size_t)b * 8 + (t + 1)) * 4096) * 64;
    h8 aq[2];
    {
        const int qrow = qblk * 64 + w * 16 + col;
        const float* qp = Qbase + (size_t)qrow * 64;
#pragma unroll
        for (int ch = 0; ch < 2; ++ch) {
            const int cc = ch * 32 + g * 8;
            const f32x4 xa = *(const f32x4*)&qp[cc];
            const f32x4 xb = *(const f32x4*)&qp[cc + 4];
            const h2 p0 = pkrtz(xa[0] * LOG2E, xa[1] * LOG2E);
            const h2 p1 = pkrtz(xa[2] * LOG2E, xa[3] * LOG2E);
            const h2 p2 = pkrtz(xb[0] * LOG2E, xb[1] * LOG2E);
            const h2 p3 = pkrtz(xb[2] * LOG2E, xb[3] * LOG2E);
            aq[ch] = (h8){p0[0], p0[1], p1[0], p1[1], p2[0], p2[1], p3[0], p3[1]};
        }
    }

    float outc0 = 0.f, outc1 = 0.f, outc2 = 0.f;

    for (int phase = 0; phase < 2; ++phase) {
        const float* kp; const float* vp; int ntile; float wgt;
        if (phase == 0) {
            kp = K + (((size_t)b * 8 + t) * 4096) * 64;
            vp = V + (((size_t)b * 8 + t) * 4096) * 3;
            ntile = 64; wgt = 0.8f;
        } else {
            kp = MK + (((size_t)b * 7 + t) * 1024) * 64;
            vp = MV + (((size_t)b * 7 + t) * 1024) * 3;
            ntile = 16; wgt = 0.2f;
        }
        {
            const float* src = kp + ((size_t)r) * 64 + c0;
            const f32x4* s4 = (const f32x4*)src;
            const f32x4 ra = s4[0], rb = s4[1], rc = s4[2], rd = s4[3];
            const h2 q0 = pkrtz(ra[0], ra[1]), q1 = pkrtz(ra[2], ra[3]);
            const h2 q2 = pkrtz(rb[0], rb[1]), q3 = pkrtz(rb[2], rb[3]);
            const h2 q4 = pkrtz(rc[0], rc[1]), q5 = pkrtz(rc[2], rc[3]);
            const h2 q6 = pkrtz(rd[0], rd[1]), q7 = pkrtz(rd[2], rd[3]);
            *(h8*)&sK[0][r][c0 ^ rs] = (h8){q0[0], q0[1], q1[0], q1[1], q2[0], q2[1], q3[0], q3[1]};
            *(h8*)&sK[0][r][(c0 + 8) ^ rs] = (h8){q4[0], q4[1], q5[0], q5[1], q6[0], q6[1], q7[0], q7[1]};
            if (tid < 192) sVT[0][vd][vr] = (__fp16)vp[tid];
        }
        __syncthreads();

        float mrun = -1e30f;
        f32x4 O = (f32x4){0.f, 0.f, 0.f, 0.f};

        for (int kt = 0; kt < ntile; ++kt) {
            const int cur = kt & 1;
            const bool have = (kt + 1) < ntile;
            f32x4 ra, rb, rc, rd; float rv = 0.f;
            if (have) {
                const float* src = kp + ((size_t)(kt + 1) * 64 + r) * 64 + c0;
                const f32x4* s4 = (const f32x4*)src;
                ra = s4[0]; rb = s4[1]; rc = s4[2]; rd = s4[3];
                if (tid < 192) rv = vp[(size_t)(kt + 1) * 192 + tid];
            }
            f32x4 acc[4];
#pragma unroll
            for (int nt = 0; nt < 4; ++nt) acc[nt] = (f32x4){0.f, 0.f, 0.f, 0.f};
#pragma unroll
            for (int ch = 0; ch < 2; ++ch) {
                h8 bh[4];
#pragma unroll
                for (int nt = 0; nt < 4; ++nt) {
                    const int rr = nt * 16 + col;
                    const int cc = (ch * 32 + g * 8) ^ ((rr & 7) << 3);
                    bh[nt] = *(const h8*)&sK[cur][rr][cc];
                }
#pragma unroll
                for (int nt = 0; nt < 4; ++nt)
                    acc[nt] = __builtin_amdgcn_mfma_f32_16x16x32_f16(bh[nt], aq[ch], acc[nt], 0, 0, 0);
            }
            {
                float tm = acc[0][0];
#pragma unroll
                for (int nt = 0; nt < 4; ++nt)
#pragma unroll
                    for (int j = 0; j < 4; ++j) tm = fmaxf(tm, acc[nt][j]);
                tm = fmaxf(tm, __shfl_xor(tm, 16));
                tm = fmaxf(tm, __shfl_xor(tm, 32));
                if (!__all(tm <= mrun)) {
                    const float mnew = fmaxf(mrun, tm);
                    const float sc = __builtin_amdgcn_exp2f(mrun - mnew);
                    O *= sc;
                    mrun = mnew;
                }
            }
#pragma unroll
            for (int nt = 0; nt < 4; ++nt) {
                const float p0 = __builtin_amdgcn_exp2f(acc[nt][0] - mrun);
                const float p1 = __builtin_amdgcn_exp2f(acc[nt][1] - mrun);
                const float p2 = __builtin_amdgcn_exp2f(acc[nt][2] - mrun);
                const float p3 = __builtin_amdgcn_exp2f(acc[nt][3] - mrun);
                const h2 pa = pkrtz(p0, p1), pb = pkrtz(p2, p3);
                const h4 pf = (h4){pa[0], pa[1], pb[0], pb[1]};
                const h4 vf = *(const h4*)&sVT[cur][col & 3][nt * 16 + 4 * g];
                O = __builtin_amdgcn_mfma_f32_16x16x16f16(vf, pf, O, 0, 0, 0);
            }
            if (have) {
                const int nb = cur ^ 1;
                const h2 q0 = pkrtz(ra[0], ra[1]), q1 = pkrtz(ra[2], ra[3]);
                const h2 q2 = pkrtz(rb[0], rb[1]), q3 = pkrtz(rb[2], rb[3]);
                const h2 q4 = pkrtz(rc[0], rc[1]), q5 = pkrtz(rc[2], rc[3]);
                const h2 q6 = pkrtz(rd[0], rd[1]), q7 = pkrtz(rd[2], rd[3]);
                *(h8*)&sK[nb][r][c0 ^ rs] = (h8){q0[0], q0[1], q1[0], q1[1], q2[0], q2[1], q3[0], q3[1]};
                *(h8*)&sK[nb][r][(c0 + 8) ^ rs] = (h8){q4[0], q4[1], q5[0], q5[1], q6[0], q6[1], q7[0], q7[1]};
                if (tid < 192) sVT[nb][vd][vr] = (__fp16)rv;
            }
            __syncthreads();
        }
        const float inv = wgt / O[3];
        outc0 += O[0] * inv;
        outc1 += O[1] * inv;
        outc2 += O[2] * inv;
    }

    if (g == 0) {
        const int q = qblk * 64 + w * 16 + col;
        float* op = OUT + (((size_t)b * 7 + t) * 4096 + (size_t)q) * 3;
        op[0] = outc0; op[1] = outc1; op[2] = outc2;
    }
}

extern "C" void kernel_launch(void* const* d_in, const int* in_sizes, int n_in,
                              void* d_out, int out_size, void* d_ws, size_t ws_size,
                              hipStream_t stream) {
    const float* K  = (const float*)d_in[0];
    const float* V  = (const float*)d_in[1];
    const float* MK = (const float*)d_in[2];
    const float* MV = (const float*)d_in[3];
    float* OUT = (float*)d_out;
    if (ws_size >= WS_NEED) {
        hipLaunchKernelGGL(kast_pre_kernel, dim3(2520), dim3(256), 0, stream,
                           K, V, MK, MV, (char*)d_ws);
        hipLaunchKernelGGL(kast_attn_kernel, dim3(1792), dim3(256), 0, stream,
                           K, (const char*)d_ws, OUT);
    } else {
        hipLaunchKernelGGL(kast_attn_fb, dim3(896), dim3(256), 0, stream,
                           K, V, MK, MV, OUT);
    }
}